// Round 1
// baseline (366.489 us; speedup 1.0000x reference)
//
#include <hip/hip_runtime.h>

#define NT 512
#define SEAS 24
constexpr int SEA_STRIDE = NT + SEAS;   // 536
constexpr int LOG_STRIDE = NT - 1;      // 511
constexpr float LN2 = 0.6931471805599453f;

__device__ __forceinline__ float frcp(float x)  { return __builtin_amdgcn_rcpf(x); }
__device__ __forceinline__ float flog2(float x) { return __builtin_amdgcn_logf(x); }

__global__ __launch_bounds__(64)
void es_fwd(const float* __restrict__ y, const int* __restrict__ idxs,
            const float* __restrict__ lev_sms_p, const float* __restrict__ init_seas_p,
            float* __restrict__ levels, float* __restrict__ seas, float* __restrict__ logd)
{
    const int s = blockIdx.x * 64 + threadIdx.x;
    const int idx = idxs[s];
    const float lsm = frcp(1.0f + __expf(-lev_sms_p[idx]));
    const float ssm = lsm; // reference computes seas_sms from lev_sms_p too (sic)

    const float* __restrict__ yrow  = y      + (size_t)s * NT;
    float* __restrict__ levrow      = levels + (size_t)s * NT;
    float* __restrict__ searow      = seas   + (size_t)s * SEA_STRIDE;
    float* __restrict__ logrow      = logd   + (size_t)s * LOG_STRIDE;

    // seasonal buffer: pos is compile-time constant after 24-step unroll -> stays in VGPRs
    float buf[SEAS];
    {
        const float4* is4 = (const float4*)(init_seas_p + (size_t)idx * SEAS); // 96B aligned
        #pragma unroll
        for (int g = 0; g < 6; ++g) {
            float4 v = is4[g];
            float a = __expf(v.x), b = __expf(v.y), c = __expf(v.z), d = __expf(v.w);
            buf[4*g+0]=a; buf[4*g+1]=b; buf[4*g+2]=c; buf[4*g+3]=d;
            float4 o; o.x=a; o.y=b; o.z=c; o.w=d;
            ((float4*)searow)[g] = o;   // seasonalities cols 0..23
        }
    }

    const float4* y4 = (const float4*)yrow; // row base 2048B aligned
    float yv[24], yn[24];
    #pragma unroll
    for (int g = 0; g < 6; ++g) {
        float4 t = y4[g];
        yv[4*g]=t.x; yv[4*g+1]=t.y; yv[4*g+2]=t.z; yv[4*g+3]=t.w;
    }

    float lev, l2prev;
    float lvv[24], svv[24];

#define STEP(POS, KI, TI) do { \
        const float yt = yv[KI]; \
        const float st = buf[POS]; \
        const float nl = lev + lsm * (yt * frcp(st) - lev); \
        const float ns = st + ssm * (yt * frcp(nl) - st); \
        const float l2 = flog2(nl); \
        lvv[KI] = nl; svv[KI] = ns; \
        logrow[(TI)-1] = (l2 - l2prev) * LN2; \
        l2prev = l2; lev = nl; buf[POS] = ns; \
    } while (0)

#define STORE_BLOCK(TBASE) do { \
        float4* lp_ = (float4*)(levrow + (TBASE)); \
        float4* sp_ = (float4*)(searow + SEAS + (TBASE)); \
        _Pragma("unroll") \
        for (int g = 0; g < 6; ++g) { \
            float4 o; o.x=lvv[4*g]; o.y=lvv[4*g+1]; o.z=lvv[4*g+2]; o.w=lvv[4*g+3]; \
            lp_[g] = o; \
            float4 p; p.x=svv[4*g]; p.y=svv[4*g+1]; p.z=svv[4*g+2]; p.w=svv[4*g+3]; \
            sp_[g] = p; \
        } \
    } while (0)

    // ---- super-block 0 : t = 0..23 (t=0 is the lev0 init, not a step) ----
    #pragma unroll
    for (int g = 0; g < 6; ++g) {               // prefetch block 1
        float4 t = y4[6+g];
        yn[4*g]=t.x; yn[4*g+1]=t.y; yn[4*g+2]=t.z; yn[4*g+3]=t.w;
    }
    lev = yv[0] * frcp(buf[0]);
    l2prev = flog2(lev);
    lvv[0] = lev;        // levels[:,0] = lev0
    svv[0] = buf[0];     // seasonalities[:,24] = init_seas[:,0]
    #pragma unroll
    for (int k = 1; k < 24; ++k) STEP(k, k, k);
    STORE_BLOCK(0);
    #pragma unroll
    for (int k = 0; k < 24; ++k) yv[k] = yn[k];

    // ---- super-blocks 1..20 : t = 24m .. 24m+23, pos = k (compile-time) ----
    for (int m = 1; m < 21; ++m) {
        if (m < 20) {
            #pragma unroll
            for (int g = 0; g < 6; ++g) {
                float4 t = y4[6*(m+1)+g];
                yn[4*g]=t.x; yn[4*g+1]=t.y; yn[4*g+2]=t.z; yn[4*g+3]=t.w;
            }
        } else {
            // tail prefetch: only groups 126,127 (t=504..511); avoid OOB read past row
            float4 t0 = y4[126];
            float4 t1 = y4[127];
            yn[0]=t0.x; yn[1]=t0.y; yn[2]=t0.z; yn[3]=t0.w;
            yn[4]=t1.x; yn[5]=t1.y; yn[6]=t1.z; yn[7]=t1.w;
        }
        const int tb = 24*m;
        #pragma unroll
        for (int k = 0; k < 24; ++k) STEP(k, k, tb + k);
        STORE_BLOCK(tb);
        #pragma unroll
        for (int k = 0; k < 24; ++k) yv[k] = yn[k];
    }

    // ---- tail: t = 504..511 (504 % 24 == 0, so pos = k) ----
    {
        const int tb = 504;
        #pragma unroll
        for (int k = 0; k < 8; ++k) STEP(k, k, tb + k);
        float4* lp = (float4*)(levrow + tb);
        float4* sp = (float4*)(searow + SEAS + tb);
        #pragma unroll
        for (int g = 0; g < 2; ++g) {
            float4 o; o.x=lvv[4*g]; o.y=lvv[4*g+1]; o.z=lvv[4*g+2]; o.w=lvv[4*g+3];
            lp[g] = o;
            float4 p; p.x=svv[4*g]; p.y=svv[4*g+1]; p.z=svv[4*g+2]; p.w=svv[4*g+3];
            sp[g] = p;
        }
    }
#undef STEP
#undef STORE_BLOCK
}

extern "C" void kernel_launch(void* const* d_in, const int* in_sizes, int n_in,
                              void* d_out, int out_size, void* d_ws, size_t ws_size,
                              hipStream_t stream)
{
    const float* y        = (const float*)d_in[0];
    const int*   idxs     = (const int*)d_in[1];
    const float* lev_sms  = (const float*)d_in[2];
    // d_in[3] (seas_sms) intentionally unused: reference derives both smoothings from lev_sms_p
    const float* init_seas = (const float*)d_in[4];
    const int n_series = in_sizes[1];

    float* levels = (float*)d_out;
    float* seasv  = levels + (size_t)n_series * NT;
    float* logdv  = seasv  + (size_t)n_series * SEA_STRIDE;

    es_fwd<<<n_series / 64, 64, 0, stream>>>(y, idxs, lev_sms, init_seas,
                                             levels, seasv, logdv);
}

// Round 2
// 346.800 us; speedup vs baseline: 1.0568x; 1.0568x over previous
//
#include <hip/hip_runtime.h>

#define NT 512
#define SEASN 24
#define TT 48

constexpr int SEA_STRIDE = NT + SEASN;   // 536
constexpr int LOG_STRIDE = NT - 1;       // 511
constexpr float LN2 = 0.6931471805599453f;

__device__ __forceinline__ float frcp(float x)  { return __builtin_amdgcn_rcpf(x); }
__device__ __forceinline__ float flog2(float x) { return __builtin_amdgcn_logf(x); }

// async global->LDS DMA, 4B per lane, dst = lds_base + lane*4 (wave-uniform base)
__device__ __forceinline__ void gl_lds4(const float* g, float* lds) {
    __builtin_amdgcn_global_load_lds(
        (const __attribute__((address_space(1))) void*)g,
        (__attribute__((address_space(3))) void*)lds, 4, 0, 0);
}

struct State { float lev, l2prev; };

// One recurrence step per thread (thread = series). Results go to LDS tiles in
// [time][series] layout so the flush can emit coalesced global stores.
// ctile as float2: (lev, seas) pair -> ds_write_b64, row stride 65 float2 (conflict-free).
// dtile: row stride 65 floats (conflict-free).
template<int T, bool FIRST>
__device__ __forceinline__ void compute_tile(const float* __restrict__ ybuf,
                                             float2* __restrict__ c2,
                                             float* __restrict__ dtile,
                                             int lane, float lsm,
                                             float (&buf)[SEASN], State& st)
{
    #pragma unroll
    for (int k = 0; k < T; ++k) {
        const int pos = k % SEASN;                 // tbase is a multiple of 24
        const float yt = ybuf[lane * 49 + k];      // bank (17*lane+k)%32 -> 2-way, free
        if (FIRST && k == 0) {
            st.lev = yt * frcp(buf[0]);            // lev0 = y0 / init_seas0
            st.l2prev = flog2(st.lev);
            c2[lane] = make_float2(st.lev, buf[0]); // levels[:,0], seas col 24 = init
            // dtile[0] intentionally unwritten (no logd for t=0; store masked in flush)
        } else {
            const float sv = buf[pos];
            const float nl = st.lev + lsm * (yt * frcp(sv) - st.lev);
            const float ns = sv + lsm * (yt * frcp(nl) - sv);  // seas_sms==lev_sms (ref sic)
            const float l2 = flog2(nl);
            c2[k * 65 + lane] = make_float2(nl, ns);
            dtile[k * 65 + lane] = (l2 - st.l2prev) * LN2;
            st.l2prev = l2; st.lev = nl; buf[pos] = ns;
        }
    }
}

// Flush: lane l <-> time tbase+l for each of the 64 series rows.
// Global stores are 4B/lane contiguous over T lanes (192B dense) -> 3-4 lines/instr.
__device__ __forceinline__ void flush_tile(const float2* __restrict__ c2,
                                           const float* __restrict__ dtile,
                                           int lane, int sbase, int tbase, int T,
                                           float* __restrict__ levels,
                                           float* __restrict__ seasv,
                                           float* __restrict__ logd)
{
    if (lane < T) {
        #pragma unroll 16
        for (int r = 0; r < 64; ++r) {
            const size_t srow = (size_t)(sbase + r);
            const float2 ls = c2[lane * 65 + r];    // bank (2l+2r)%32 -> even, optimal
            const float dv = dtile[lane * 65 + r];  // bank (l+r)%32 -> free
            levels[srow * NT + tbase + lane] = ls.x;
            seasv[srow * SEA_STRIDE + SEASN + tbase + lane] = ls.y;
            if (tbase + lane > 0)
                logd[srow * LOG_STRIDE + tbase + lane - 1] = dv;
        }
    }
}

__global__ __launch_bounds__(64)
void es_fwd(const float* __restrict__ y, const int* __restrict__ idxs,
            const float* __restrict__ lev_sms_p, const float* __restrict__ init_seas_p,
            float* __restrict__ levels, float* __restrict__ seasv,
            float* __restrict__ logd)
{
    __shared__ float ybuf[64 * 49];                    // [series][49] 12.25 KB
    __shared__ __align__(16) float2 c2[TT * 65];       // [time][65] (lev,seas) 24.4 KB
    __shared__ float dtile[TT * 65];                   // [time][65] logd 12.2 KB

    const int lane = threadIdx.x;          // series within block
    const int sbase = blockIdx.x * 64;
    const int s = sbase + lane;
    const int idx = idxs[s];
    const float lsm = frcp(1.0f + __expf(-lev_sms_p[idx]));

    float buf[SEASN];
    {   // init seasonal buffer + store seas cols 0..23 (96B/row, as in R1 - small traffic)
        float* searow = seasv + (size_t)s * SEA_STRIDE;
        const float4* is4 = (const float4*)(init_seas_p + (size_t)idx * SEASN);
        #pragma unroll
        for (int g = 0; g < 6; ++g) {
            float4 v = is4[g];
            float a = __expf(v.x), b = __expf(v.y), c = __expf(v.z), d = __expf(v.w);
            buf[4*g]=a; buf[4*g+1]=b; buf[4*g+2]=c; buf[4*g+3]=d;
            float4 o; o.x=a; o.y=b; o.z=c; o.w=d;
            ((float4*)searow)[g] = o;
        }
    }

    // per-lane global source: lane = time offset within the staged row
    const float* ysrc = y + (size_t)sbase * NT + lane;
    auto stage = [&](int tbase, int cols) {
        if (lane < cols) {
            const float* g = ysrc + tbase;
            #pragma unroll
            for (int r = 0; r < 64; ++r)
                gl_lds4(g + (size_t)r * NT, &ybuf[r * 49]);  // dense 4B*cols per row
        }
    };

    State st;

    stage(0, TT);
    __builtin_amdgcn_s_waitcnt(0);
    compute_tile<TT, true>(ybuf, c2, dtile, lane, lsm, buf, st);

    stage(TT, TT);
    flush_tile(c2, dtile, lane, sbase, 0, TT, levels, seasv, logd);
    __builtin_amdgcn_s_waitcnt(0);

    for (int m = 1; m <= 9; ++m) {
        compute_tile<TT, false>(ybuf, c2, dtile, lane, lsm, buf, st);
        if (m < 9) stage((m + 1) * TT, TT);
        else       stage(480, 32);                      // tail tile: 32 cols
        flush_tile(c2, dtile, lane, sbase, m * TT, TT, levels, seasv, logd);
        __builtin_amdgcn_s_waitcnt(0);
    }

    compute_tile<32, false>(ybuf, c2, dtile, lane, lsm, buf, st);
    flush_tile(c2, dtile, lane, sbase, 480, 32, levels, seasv, logd);
}

extern "C" void kernel_launch(void* const* d_in, const int* in_sizes, int n_in,
                              void* d_out, int out_size, void* d_ws, size_t ws_size,
                              hipStream_t stream)
{
    const float* y         = (const float*)d_in[0];
    const int*   idxs      = (const int*)d_in[1];
    const float* lev_sms   = (const float*)d_in[2];
    // d_in[3] (seas_sms) unused: reference derives both smoothings from lev_sms_p
    const float* init_seas = (const float*)d_in[4];
    const int n_series = in_sizes[1];

    float* levels = (float*)d_out;
    float* seasv  = levels + (size_t)n_series * NT;
    float* logdv  = seasv  + (size_t)n_series * SEA_STRIDE;

    es_fwd<<<n_series / 64, 64, 0, stream>>>(y, idxs, lev_sms, init_seas,
                                             levels, seasv, logdv);
}

// Round 3
// 329.499 us; speedup vs baseline: 1.1123x; 1.0525x over previous
//
#include <hip/hip_runtime.h>

#define NT 512
#define SEASN 24
#define TT 64
#define YS 65                     // LDS tile row stride (floats): (65*l+k)%32=(l+k)%32 -> 2-way = free

constexpr int SEA_STRIDE = NT + SEASN;   // 536
constexpr int LOG_STRIDE = NT - 1;       // 511
constexpr float LN2 = 0.6931471805599453f;

__device__ __forceinline__ float frcp(float x)  { return __builtin_amdgcn_rcpf(x); }
__device__ __forceinline__ float flog2(float x) { return __builtin_amdgcn_logf(x); }

// async global->LDS DMA: 4B/lane, dst = wave-uniform base + lane*4
__device__ __forceinline__ void gl_lds4(const float* g, float* lds) {
    __builtin_amdgcn_global_load_lds(
        (const __attribute__((address_space(1))) void*)g,
        (__attribute__((address_space(3))) void*)lds, 4, 0, 0);
}

// 64 recurrence steps for this lane's series. pos = (PHASE+k)%24 is compile-time
// (PHASE = (64*m)%24 in {0,16,8}), so the seasonal buffer stays in 24 VGPRs and all
// LDS addresses are vaddr + imm-offset (zero address arithmetic in the loop).
template<int PHASE, bool FIRST>
__device__ __forceinline__ void compute_tile(const float* __restrict__ yb,
                                             float* __restrict__ lt,
                                             float* __restrict__ st,
                                             float* __restrict__ dt,
                                             float lsm, float (&buf)[SEASN],
                                             float& lev, float& l2p)
{
    #pragma unroll
    for (int k = 0; k < TT; ++k) {
        const int pos = (PHASE + k) % SEASN;
        const float yt = yb[k];
        if (FIRST && k == 0) {
            lev = yt * frcp(buf[0]);          // lev0 = y0 / init_seas0
            l2p = flog2(lev);
            lt[0] = lev;                      // levels[:,0]
            st[0] = buf[0];                   // seasonalities col 24 = init_seas[:,0]
            // dt[0] unwritten; masked at flush
        } else {
            const float sv = buf[pos];
            const float nl = lev + lsm * (yt * frcp(sv) - lev);
            const float ns = sv + lsm * (yt * frcp(nl) - sv);  // seas_sms == lev_sms (ref sic)
            const float l2 = flog2(nl);
            lt[k] = nl; st[k] = ns; dt[k] = (l2 - l2p) * LN2;
            l2p = l2; lev = nl; buf[pos] = ns;
        }
    }
}

// Flush tile m: lane = q + 16*rr (q = time-quad, rr = row offset). 16 iters cover 64 rows.
// Lanes 0..15 store 256B dense per row -> 4 full lines per 16-lane group.
template<bool FIRSTTILE>
__device__ __forceinline__ void flush_tile(const float* __restrict__ lt,
                                           const float* __restrict__ st,
                                           const float* __restrict__ dt,
                                           int q, int rr, int sbase, int tbase,
                                           float* __restrict__ levels,
                                           float* __restrict__ seasv,
                                           float* __restrict__ logd)
{
    #pragma unroll
    for (int i = 0; i < 16; ++i) {
        const int r = 4 * i + rr;
        const size_t srow = (size_t)(sbase + r);
        const int off = r * YS + 4 * q;
        float4 lv = make_float4(lt[off], lt[off+1], lt[off+2], lt[off+3]);
        float4 sv = make_float4(st[off], st[off+1], st[off+2], st[off+3]);
        // levels: 2048*s + 256*m + 16*q -> 16B aligned
        *(float4*)(levels + srow * NT + tbase + 4 * q) = lv;
        // seasv: 2144*s + 96 + 256*m + 16*q -> 16B aligned
        *(float4*)(seasv + srow * SEA_STRIDE + SEASN + tbase + 4 * q) = sv;
        // logd row stride 511 -> only 4B alignment; scalar stores (still 256B dense/row-group)
        float* dp = logd + srow * LOG_STRIDE + tbase + 4 * q - 1;
        if (FIRSTTILE && q == 0) {
            dp[1] = dt[off+1]; dp[2] = dt[off+2]; dp[3] = dt[off+3];  // skip t=0
        } else {
            dp[0] = dt[off]; dp[1] = dt[off+1]; dp[2] = dt[off+2]; dp[3] = dt[off+3];
        }
    }
}

__global__ __launch_bounds__(64)
void es_fwd(const float* __restrict__ y, const int* __restrict__ idxs,
            const float* __restrict__ lev_sms_p, const float* __restrict__ init_seas_p,
            float* __restrict__ levels, float* __restrict__ seasv,
            float* __restrict__ logd)
{
    __shared__ float ybuf [64 * YS];   // [series][time] y stage
    __shared__ float ltile[64 * YS];   // [series][time] levels
    __shared__ float stile[64 * YS];   // [series][time] seasons
    __shared__ float dtile[64 * YS];   // [series][time] log-diffs          total 66.6 KB

    const int lane  = threadIdx.x;     // = series within block
    const int sbase = blockIdx.x * 64;
    const int q  = lane & 15;
    const int rr = lane >> 4;

    auto stage = [&](int m) {
        const float* g = y + (size_t)sbase * NT + m * TT + lane;
        #pragma unroll
        for (int r = 0; r < 64; ++r)
            gl_lds4(g + (size_t)r * NT, &ybuf[r * YS]);   // 256B dense per series row
    };

    stage(0);                                             // overlap DMA with init gathers

    const int idx = idxs[sbase + lane];
    const float lsm = frcp(1.0f + __expf(-lev_sms_p[idx]));  // sigmoid

    float buf[SEASN];
    {
        const float4* is4 = (const float4*)(init_seas_p + (size_t)idx * SEASN);
        #pragma unroll
        for (int g = 0; g < 6; ++g) {
            float4 v = is4[g];
            buf[4*g+0] = __expf(v.x); buf[4*g+1] = __expf(v.y);
            buf[4*g+2] = __expf(v.z); buf[4*g+3] = __expf(v.w);
            #pragma unroll
            for (int j = 0; j < 4; ++j)
                ltile[lane * YS + 4*g + j] = buf[4*g+j];  // stage init cols for transpose-flush
        }
    }

    // flush seasv cols 0..23 coalesced (reuses ltile before tile 0 overwrites it)
    if (q < 6) {
        #pragma unroll
        for (int i = 0; i < 16; ++i) {
            const int r = 4 * i + rr;
            const size_t srow = (size_t)(sbase + r);
            const int off = r * YS + 4 * q;
            float4 v = make_float4(ltile[off], ltile[off+1], ltile[off+2], ltile[off+3]);
            *(float4*)(seasv + srow * SEA_STRIDE + 4 * q) = v;   // 2144*s + 16*q aligned
        }
    }

    float lev, l2p;
    const float* yb = &ybuf[lane * YS];
    float* lt = &ltile[lane * YS];
    float* st = &stile[lane * YS];
    float* dt = &dtile[lane * YS];

    __builtin_amdgcn_s_waitcnt(0);                        // y tile 0 + gathers resident
    compute_tile<0, true >(yb, lt, st, dt, lsm, buf, lev, l2p);
    stage(1);
    flush_tile<true >(ltile, stile, dtile, q, rr, sbase, 0 * TT, levels, seasv, logd);
    __builtin_amdgcn_s_waitcnt(0);

#define TILE(M, PHASE, LAST) \
    compute_tile<PHASE, false>(yb, lt, st, dt, lsm, buf, lev, l2p); \
    if (!(LAST)) stage((M) + 1); \
    flush_tile<false>(ltile, stile, dtile, q, rr, sbase, (M) * TT, levels, seasv, logd); \
    if (!(LAST)) __builtin_amdgcn_s_waitcnt(0);

    TILE(1, 16, false)
    TILE(2,  8, false)
    TILE(3,  0, false)
    TILE(4, 16, false)
    TILE(5,  8, false)
    TILE(6,  0, false)
    TILE(7, 16, true)
#undef TILE
}

extern "C" void kernel_launch(void* const* d_in, const int* in_sizes, int n_in,
                              void* d_out, int out_size, void* d_ws, size_t ws_size,
                              hipStream_t stream)
{
    const float* y         = (const float*)d_in[0];
    const int*   idxs      = (const int*)d_in[1];
    const float* lev_sms   = (const float*)d_in[2];
    // d_in[3] (seas_sms) unused: reference derives both smoothings from lev_sms_p
    const float* init_seas = (const float*)d_in[4];
    const int n_series = in_sizes[1];

    float* levels = (float*)d_out;
    float* seasv  = levels + (size_t)n_series * NT;
    float* logdv  = seasv  + (size_t)n_series * SEA_STRIDE;

    es_fwd<<<n_series / 64, 64, 0, stream>>>(y, idxs, lev_sms, init_seas,
                                             levels, seasv, logdv);
}